// Round 1
// baseline (474.821 us; speedup 1.0000x reference)
//
#include <hip/hip_runtime.h>

// Local cost-volume correlation, fp32, vector-ALU path.
// out[b, dy*9+dx, h, w] = (1/256) * sum_c in1[b,c,h,w] * in2[b,c,h+dy-4,w+dx-4]
//
// Grid: 1728 blocks = 8 b x 12 h-tiles x 2 w-halves x 9 dy, XCD-swizzled so the
// 9 dy-blocks of one tile share blockIdx%8 (same-XCD L2 reuse of in1/in2).
// Block: 64 threads (1 wave) = 8 h-rows x 8 w-groups; each thread owns
// 8 w-pixels x 9 dx = 72 accumulators, loops all 256 channels in chunks of 4.
// Per channel per thread: 2x float4 in1 (global), 4x ds_read_b128 in2 window
// (16 floats), 72 FMAs -> 4.5 FMA per LDS lane-read.

#define CH 256
#define HH 96
#define WW 128
#define HT 8    // tile rows
#define WT 64   // tile cols
#define CK 4    // channel chunk staged in LDS
#define S2W 72  // staged in2 width (64 + 2*4 halo)
#define S2S 84  // padded LDS row stride (floats): 84*hl mod 32 spreads banks

__global__ __launch_bounds__(64) void corr_kernel(
    const float* __restrict__ in1, const float* __restrict__ in2,
    float* __restrict__ out)
{
  __shared__ float s2[CK * HT * S2S];  // 10752 B

  // ---- block decode with XCD swizzle: same tile -> same blockIdx%8 ----
  const int j   = blockIdx.x;
  const int xcd = j & 7;
  const int s   = j >> 3;          // 0..215
  const int dy  = s % 9;
  const int tq  = s / 9;           // 0..23
  const int tile = tq * 8 + xcd;   // 0..191
  const int wh  = tile & 1;
  const int tr  = tile >> 1;       // 0..95
  const int ht  = tr % 12;
  const int b   = tr / 12;

  const int h0    = ht * HT;
  const int wbase = wh * WT;
  const int dyo   = dy - 4;

  const int t  = threadIdx.x;
  const int hl = t >> 3;           // 0..7
  const int wl = (t & 7) << 3;     // 0,8,...,56
  const int h  = h0 + hl;

  const float* __restrict__ in1b = in1 + (size_t)b * CH * HH * WW;
  const float* __restrict__ in2b = in2 + (size_t)b * CH * HH * WW;

  float acc[8][9];
#pragma unroll
  for (int p = 0; p < 8; ++p)
#pragma unroll
    for (int d = 0; d < 9; ++d) acc[p][d] = 0.f;

  for (int c0 = 0; c0 < CH; c0 += CK) {
    __syncthreads();
    // ---- stage in2: CK channels x HT rows x 72 floats (zero-padded) ----
    // flat float4 index f = t + 64*m over 4*8*18 = 576 float4s
#pragma unroll
    for (int m = 0; m < 9; ++m) {
      int f   = t + m * 64;
      int cc  = f / (HT * (S2W / 4));            // /144
      int rem = f - cc * (HT * (S2W / 4));
      int rr  = rem / (S2W / 4);                 // /18
      int i4  = rem - rr * (S2W / 4);
      int i   = i4 * 4;
      int gr  = h0 + dyo + rr;
      int gw  = wbase - 4 + i;                   // multiple of 4 -> f4 fully in/out
      float4 v = make_float4(0.f, 0.f, 0.f, 0.f);
      if ((unsigned)gr < (unsigned)HH && (unsigned)gw < (unsigned)WW)
        v = *(const float4*)(in2b + ((size_t)(c0 + cc) * HH + gr) * WW + gw);
      *(float4*)(&s2[(cc * HT + rr) * S2S + i]) = v;
    }
    __syncthreads();

    // ---- compute ----
#pragma unroll
    for (int cc = 0; cc < CK; ++cc) {
      const float* p1 = in1b + ((size_t)(c0 + cc) * HH + h) * WW + wbase + wl;
      float4 a0 = *(const float4*)p1;
      float4 a1 = *(const float4*)(p1 + 4);
      float a[8] = {a0.x, a0.y, a0.z, a0.w, a1.x, a1.y, a1.z, a1.w};
      float bv[16];
      const float* ps = &s2[(cc * HT + hl) * S2S + wl];
#pragma unroll
      for (int q = 0; q < 4; ++q) {
        float4 bb = *(const float4*)(ps + q * 4);
        bv[q * 4 + 0] = bb.x; bv[q * 4 + 1] = bb.y;
        bv[q * 4 + 2] = bb.z; bv[q * 4 + 3] = bb.w;
      }
#pragma unroll
      for (int p = 0; p < 8; ++p)
#pragma unroll
        for (int d = 0; d < 9; ++d)
          acc[p][d] = fmaf(a[p], bv[p + d], acc[p][d]);
    }
  }

  // ---- epilogue: mean over C, coalesced float4 stores ----
  const float sc = 1.0f / (float)CH;
#pragma unroll
  for (int d = 0; d < 9; ++d) {
    float* po = out + ((((size_t)b * 81 + (dy * 9 + d)) * HH + h) * WW + wbase + wl);
    float4 o0 = make_float4(acc[0][d] * sc, acc[1][d] * sc,
                            acc[2][d] * sc, acc[3][d] * sc);
    float4 o1 = make_float4(acc[4][d] * sc, acc[5][d] * sc,
                            acc[6][d] * sc, acc[7][d] * sc);
    *(float4*)po       = o0;
    *(float4*)(po + 4) = o1;
  }
}

extern "C" void kernel_launch(void* const* d_in, const int* in_sizes, int n_in,
                              void* d_out, int out_size, void* d_ws, size_t ws_size,
                              hipStream_t stream) {
  const float* in1 = (const float*)d_in[0];
  const float* in2 = (const float*)d_in[1];
  float* out = (float*)d_out;
  hipLaunchKernelGGL(corr_kernel, dim3(1728), dim3(64), 0, stream, in1, in2, out);
}

// Round 2
// 377.584 us; speedup vs baseline: 1.2575x; 1.2575x over previous
//
#include <hip/hip_runtime.h>

// Local cost-volume correlation, fp32, vector-ALU, LDS-free.
// out[b, dy*9+dx, h, w] = (1/256) * sum_c in1[b,c,h,w] * in2[b,c,h+dy-4,w+dx-4]
//
// R2 redesign vs R1 (337 us, VALUBusy 15.6%, Occ 19.7%, 4.3e7 LDS conflicts):
//   - no LDS, no barriers: in2 windows read direct from global via L1/L2
//   - 4 px/thread (36 accs) -> 3456 waves = 13.5 waves/CU (42% occ) for latency hiding
//   - edge cols: clamped addresses + cndmask kill (branch-free); edge rows: exec-mask
//   - XCD swizzle kept: 9 dy-blocks of a tile share blockIdx%8 (L2 reuse proven in R1)

#define CH 256
#define HH 96
#define WW 128
#define CSTRIDE (HH * WW)  // 12288 floats per channel plane

__global__ __launch_bounds__(256) void corr_kernel(
    const float* __restrict__ in1, const float* __restrict__ in2,
    float* __restrict__ out)
{
  // ---- block decode with XCD swizzle (grid = 864 = 8 xcd * 108) ----
  const int j   = blockIdx.x;
  const int xcd = j & 7;
  const int s   = j >> 3;          // 0..107
  const int dy  = s % 9;
  const int tq  = s / 9;           // 0..11
  const int tile = tq * 8 + xcd;   // 0..95
  const int wh  = tile & 1;
  const int tr  = tile >> 1;       // 0..47
  const int ht  = tr % 6;          // 6 h-tiles of 16 rows
  const int b   = tr / 6;

  const int h0    = ht * 16;
  const int wbase = wh * 64;
  const int dyo   = dy - 4;

  // ---- thread decode: 16 rows x 16 col-groups, 4 px each ----
  const int t  = threadIdx.x;
  const int hl = t >> 4;           // 0..15
  const int wl = (t & 15) << 2;    // 0,4,...,60
  const int h  = h0 + hl;          // in [0,96)
  const int wq = wbase + wl - 4;   // window start col, in [-4,120]
  const int r2 = h + dyo;          // in2 row, may be out of range

  const bool row_ok = (unsigned)r2 < (unsigned)HH;
  const bool lkill  = (wq < 0);          // bv[0..3] invalid  (only wq==-4)
  const bool rkill  = (wq > 116);        // bv[8..11] invalid (only wq==120)

  float acc[4][9];
#pragma unroll
  for (int p = 0; p < 4; ++p)
#pragma unroll
    for (int d = 0; d < 9; ++d) acc[p][d] = 0.f;

  if (row_ok) {
    const int wb0 = (wq < 0) ? 0 : wq;         // clamped, aligned, in-bounds
    const int wb2 = (wq + 8 > 124) ? 124 : wq + 8;
    const float* pa  = in1 + ((size_t)b * CH * HH + h) * WW + wbase + wl;
    const float* pb0 = in2 + ((size_t)b * CH * HH + r2) * WW + wb0;
    const float* pb1 = in2 + ((size_t)b * CH * HH + r2) * WW + (wq + 4);
    const float* pb2 = in2 + ((size_t)b * CH * HH + r2) * WW + wb2;

#pragma unroll 2
    for (int c = 0; c < CH; ++c) {
      float4 a  = *(const float4*)pa;
      float4 b0 = *(const float4*)pb0;
      float4 b1 = *(const float4*)pb1;
      float4 b2 = *(const float4*)pb2;
      pa += CSTRIDE; pb0 += CSTRIDE; pb1 += CSTRIDE; pb2 += CSTRIDE;

      // branch-free edge kill: per-lane-constant masks -> v_cndmask
      b0.x = lkill ? 0.f : b0.x; b0.y = lkill ? 0.f : b0.y;
      b0.z = lkill ? 0.f : b0.z; b0.w = lkill ? 0.f : b0.w;
      b2.x = rkill ? 0.f : b2.x; b2.y = rkill ? 0.f : b2.y;
      b2.z = rkill ? 0.f : b2.z; b2.w = rkill ? 0.f : b2.w;

      const float av[4] = {a.x, a.y, a.z, a.w};
      const float bv[12] = {b0.x, b0.y, b0.z, b0.w,
                            b1.x, b1.y, b1.z, b1.w,
                            b2.x, b2.y, b2.z, b2.w};
#pragma unroll
      for (int p = 0; p < 4; ++p)
#pragma unroll
        for (int d = 0; d < 9; ++d)
          acc[p][d] = fmaf(av[p], bv[p + d], acc[p][d]);
    }
  }

  // ---- epilogue: mean over C, coalesced float4 stores (zeros if !row_ok) ----
  const float sc = 1.0f / (float)CH;
  float* po = out + (((size_t)b * 81 + dy * 9) * HH + h) * WW + wbase + wl;
#pragma unroll
  for (int d = 0; d < 9; ++d) {
    *(float4*)po = make_float4(acc[0][d] * sc, acc[1][d] * sc,
                               acc[2][d] * sc, acc[3][d] * sc);
    po += (size_t)CSTRIDE;  // next displacement plane
  }
}

extern "C" void kernel_launch(void* const* d_in, const int* in_sizes, int n_in,
                              void* d_out, int out_size, void* d_ws, size_t ws_size,
                              hipStream_t stream) {
  const float* in1 = (const float*)d_in[0];
  const float* in2 = (const float*)d_in[1];
  float* out = (float*)d_out;
  hipLaunchKernelGGL(corr_kernel, dim3(864), dim3(256), 0, stream, in1, in2, out);
}